// Round 1
// baseline (971.905 us; speedup 1.0000x reference)
//
#include <hip/hip_runtime.h>

typedef unsigned int uint32;
typedef unsigned short ushort16;

#define B_SZ 16384
#define N0_SZ 1024
#define C_CLS 12
#define K_CL 64
#define D_DIM 3
#define WALL_ROWS 832   // 64 (12 y0 cols + 52 zero pad) + 12*64 ybin rows
#define TB 32
#define NGRP 13
#define MARGIN 0.04f

// ---------- bf16 helpers (manual RNE; no API ambiguity) ----------
__device__ __forceinline__ ushort16 f2bf(float f) {
  uint32 u = __float_as_uint(f);
  u += 0x7fffu + ((u >> 16) & 1u);
  return (ushort16)(u >> 16);
}
__device__ __forceinline__ float bflo(uint32 u) { return __uint_as_float(u << 16); }
__device__ __forceinline__ float bfhi(uint32 u) { return __uint_as_float(u & 0xffff0000u); }
__device__ __forceinline__ float bf2f(ushort16 h) { return __uint_as_float(((uint32)h) << 16); }

// ---------- prep: Wall = [Wfc^T (12) | 52 zeros | Wbin (768)] as bf16 ----------
__global__ void prep_wall(const float* __restrict__ Wfc, const float* __restrict__ Wbin,
                          ushort16* __restrict__ Wall) {
  int idx = blockIdx.x * 256 + threadIdx.x;      // exactly 832*1024 threads
  int j = idx >> 10, n = idx & 1023;
  float v = 0.f;
  if (j < 12) v = Wfc[n * 12 + j];
  else if (j >= 64) v = Wbin[(size_t)(j - 64) * 1024 + n];
  Wall[idx] = f2bf(v);
}

// ---------- prep: Wres[c,k,n,d] -> Wres_b[c][k][d][n] bf16 ----------
__global__ void prep_wres(const float* __restrict__ Wres, ushort16* __restrict__ Wres_b) {
  int idx = blockIdx.x * 256 + threadIdx.x;      // exactly 12*64*3*1024 threads
  int n = idx & 1023;
  int d = (idx >> 10) % 3;
  int ck = idx / 3072;
  Wres_b[idx] = f2bf(Wres[((size_t)ck * 1024 + n) * 3 + d]);
}

// ---------- main fused GEMM: y0 + ybin(bf16) ----------
__global__ __launch_bounds__(256) void gemm_main(
    const float* __restrict__ x, const float* __restrict__ bfc,
    const float* __restrict__ bbin, const ushort16* __restrict__ Wall,
    ushort16* __restrict__ ybin, float* __restrict__ out) {
  extern __shared__ ushort16 smem[];
  ushort16* xs = smem;                    // [32][1026] bf16 (pad +2 breaks bank collisions)
  uint32* xsu = (uint32*)xs;
  uint32* wtu = (uint32*)(smem + 32 * 1026);  // wt: [64][34] bf16
  const int t = threadIdx.x;
  const int b0 = blockIdx.x * TB;

  // stage 32 rows of x, f32 -> bf16, coalesced float4 loads
  for (int i = 0; i < 32; ++i) {
    int f4 = t + 256 * i;                // 8192 float4s total
    int row = f4 >> 8, k4 = f4 & 255;
    float4 v = *(const float4*)(x + (size_t)(b0 + row) * 1024 + k4 * 4);
    int ue = row * 513 + k4 * 2;
    xsu[ue]     = ((uint32)f2bf(v.y) << 16) | (uint32)f2bf(v.x);
    xsu[ue + 1] = ((uint32)f2bf(v.w) << 16) | (uint32)f2bf(v.z);
  }

  const int tx = t & 15, ty = t >> 4;    // thread -> (4 cols, 2 rows) tile
  for (int g = 0; g < NGRP; ++g) {
    float acc[8];
#pragma unroll
    for (int i = 0; i < 8; ++i) acc[i] = 0.f;
    for (int kc = 0; kc < 1024; kc += 32) {
      __syncthreads();                   // protect wt (and xs on first iter)
      {
        int row = t >> 2, k0 = (t & 3) * 8;
        uint4 wv = *(const uint4*)(Wall + (size_t)(g * 64 + row) * 1024 + kc + k0);
        int wi = row * 17 + (k0 >> 1);
        wtu[wi] = wv.x; wtu[wi + 1] = wv.y; wtu[wi + 2] = wv.z; wtu[wi + 3] = wv.w;
      }
      __syncthreads();
      int xbase0 = (2 * ty) * 513 + (kc >> 1);
      int xbase1 = xbase0 + 513;
#pragma unroll
      for (int k2 = 0; k2 < 16; ++k2) {
        uint32 ux0 = xsu[xbase0 + k2];
        uint32 ux1 = xsu[xbase1 + k2];
        float x00 = bflo(ux0), x01 = bfhi(ux0);
        float x10 = bflo(ux1), x11 = bfhi(ux1);
#pragma unroll
        for (int i = 0; i < 4; ++i) {
          uint32 uw = wtu[(4 * tx + i) * 17 + k2];
          float w0 = bflo(uw), w1 = bfhi(uw);
          acc[i]     = fmaf(x01, w1, fmaf(x00, w0, acc[i]));
          acc[4 + i] = fmaf(x11, w1, fmaf(x10, w0, acc[4 + i]));
        }
      }
    }
    // epilogue for this group
#pragma unroll
    for (int rr = 0; rr < 2; ++rr) {
      int gb = b0 + 2 * ty + rr;
#pragma unroll
      for (int i = 0; i < 4; ++i) {
        int jj = 4 * tx + i;
        float val = acc[rr * 4 + i];
        if (g == 0) {
          if (jj < 12) out[(size_t)gb * 12 + jj] = val + bfc[jj];
        } else {
          int c = g - 1;
          val += bbin[c * 64 + jj];
          ybin[((size_t)gb * 12 + c) * 64 + jj] = f2bf(val);
        }
      }
    }
  }
}

// ---------- argmax (+f64 rescue) + selected residual + y1 ----------
__global__ __launch_bounds__(256) void select_kernel(
    const float* __restrict__ x, const float* __restrict__ Wbin,
    const float* __restrict__ bbin, const float* __restrict__ bres,
    const float* __restrict__ centers, const ushort16* __restrict__ Wres_b,
    const ushort16* __restrict__ ybin, float* __restrict__ out) {
  const int lane = threadIdx.x & 63;
  const int w = threadIdx.x >> 6;
  const int p = blockIdx.x * 4 + w;      // pair id < B*C
  const int b = p / 12, c = p % 12;

  float xv[16];
#pragma unroll
  for (int j = 0; j < 16; ++j) xv[j] = x[(size_t)b * 1024 + lane + 64 * j];

  float v = bf2f(ybin[(size_t)p * 64 + lane]);
  // wave-wide top-2 (value,index) butterfly reduce; ties -> smaller k (first-max)
  float m1 = v, m2 = -3.4e38f;
  int k1 = lane;
  for (int off = 32; off; off >>= 1) {
    float om1 = __shfl_xor(m1, off);
    int   ok1 = __shfl_xor(k1, off);
    float om2 = __shfl_xor(m2, off);
    bool take = (om1 > m1) || (om1 == m1 && ok1 < k1);
    float lose = take ? m1 : om1;
    m2 = fmaxf(fmaxf(m2, om2), lose);
    if (take) { m1 = om1; k1 = ok1; }
  }
  int ind = k1;
  if (m1 - m2 <= MARGIN) {
    // exact f64 rescue over candidate k's (approx within MARGIN of max)
    unsigned long long mask = __ballot(v >= m1 - MARGIN);
    double best = -1.0e300;
    int bk = 0;
    while (mask) {
      int k = __ffsll(mask) - 1;
      mask &= (mask - 1);
      const float* wrow = Wbin + ((size_t)c * 64 + k) * 1024;
      double s = 0.0;
#pragma unroll
      for (int j = 0; j < 16; ++j)
        s += (double)xv[j] * (double)wrow[lane + 64 * j];
      for (int off = 32; off; off >>= 1) s += __shfl_xor(s, off);
      s += (double)bbin[c * 64 + k];
      if (s > best) { best = s; bk = k; }   // ascending k + strict > = first max
    }
    ind = bk;
  }
  // selected residual: dot(x_row, Wres[c,ind,:,d]) for d=0..2
  const ushort16* wr = Wres_b + ((size_t)(c * 64 + ind) * 3) * 1024;
  float a0 = 0.f, a1 = 0.f, a2 = 0.f;
#pragma unroll
  for (int j = 0; j < 16; ++j) {
    float xf = xv[j];
    int o = lane + 64 * j;
    a0 = fmaf(xf, bf2f(wr[o]),        a0);
    a1 = fmaf(xf, bf2f(wr[1024 + o]), a1);
    a2 = fmaf(xf, bf2f(wr[2048 + o]), a2);
  }
  for (int off = 32; off; off >>= 1) {
    a0 += __shfl_xor(a0, off);
    a1 += __shfl_xor(a1, off);
    a2 += __shfl_xor(a2, off);
  }
  if (lane == 0) {
    size_t base = (size_t)B_SZ * 12 + (size_t)b * 36;   // y1 region, [B][D][C]
    int ck = c * 64 + ind;
    out[base + 0 * 12 + c] = centers[ind * 3 + 0] + bres[ck * 3 + 0] + a0;
    out[base + 1 * 12 + c] = centers[ind * 3 + 1] + bres[ck * 3 + 1] + a1;
    out[base + 2 * 12 + c] = centers[ind * 3 + 2] + bres[ck * 3 + 2] + a2;
  }
}

extern "C" void kernel_launch(void* const* d_in, const int* in_sizes, int n_in,
                              void* d_out, int out_size, void* d_ws, size_t ws_size,
                              hipStream_t stream) {
  const float* x       = (const float*)d_in[0];
  const float* Wfc     = (const float*)d_in[1];
  const float* bfc     = (const float*)d_in[2];
  const float* Wbin    = (const float*)d_in[3];
  const float* bbin    = (const float*)d_in[4];
  const float* Wres    = (const float*)d_in[5];
  const float* bres    = (const float*)d_in[6];
  const float* centers = (const float*)d_in[7];
  float* out = (float*)d_out;

  char* ws = (char*)d_ws;
  ushort16* Wall   = (ushort16*)ws;                                 // 832*1024*2   = 1,703,936 B
  ushort16* Wres_b = (ushort16*)(ws + 1703936);                     // 2,359,296*2  = 4,718,592 B
  ushort16* ybin   = (ushort16*)(ws + 1703936 + 4718592);           // 12,582,912*2 = 25,165,824 B
  // total ws use: ~30.1 MiB

  size_t smem = (size_t)(32 * 1026 + 64 * 34) * sizeof(ushort16);   // 70,016 B (>64K -> raise cap)
  (void)hipFuncSetAttribute((const void*)gemm_main,
                            hipFuncAttributeMaxDynamicSharedMemorySize, (int)smem);

  prep_wall<<<3328, 256, 0, stream>>>(Wfc, Wbin, Wall);
  prep_wres<<<9216, 256, 0, stream>>>(Wres, Wres_b);
  gemm_main<<<512, 256, smem, stream>>>(x, bfc, bbin, Wall, ybin, out);
  select_kernel<<<49152, 256, 0, stream>>>(x, Wbin, bbin, bres, centers, Wres_b, ybin, out);
}

// Round 2
// 252.565 us; speedup vs baseline: 3.8481x; 3.8481x over previous
//
#include <hip/hip_runtime.h>

typedef unsigned int uint32;
typedef unsigned short ushort16;
typedef __attribute__((ext_vector_type(8))) short bf16x8;
typedef __attribute__((ext_vector_type(4))) float f32x4;
typedef __attribute__((ext_vector_type(4))) uint32 u32x4;

#define B_SZ 16384
#define MARGIN 0.04f

// ---------- bf16 helpers (manual RNE) ----------
__device__ __forceinline__ ushort16 f2bf(float f) {
  uint32 u = __float_as_uint(f);
  u += 0x7fffu + ((u >> 16) & 1u);
  return (ushort16)(u >> 16);
}
__device__ __forceinline__ float bf2f(ushort16 h) { return __uint_as_float(((uint32)h) << 16); }
__device__ __forceinline__ uint32 pk2(float lo, float hi) {
  return ((uint32)f2bf(hi) << 16) | (uint32)f2bf(lo);
}

// ---------- prep: Wall = [Wfc^T (12) | 52 zeros | Wbin (768)] as bf16 ----------
__global__ void prep_wall(const float* __restrict__ Wfc, const float* __restrict__ Wbin,
                          ushort16* __restrict__ Wall) {
  int idx = blockIdx.x * 256 + threadIdx.x;      // 832*1024 threads
  int j = idx >> 10, n = idx & 1023;
  float v = 0.f;
  if (j < 12) v = Wfc[n * 12 + j];
  else if (j >= 64) v = Wbin[(size_t)(j - 64) * 1024 + n];
  Wall[idx] = f2bf(v);
}

// ---------- prep: Wres[c,k,n,d] -> Wres_b[c][k][d][n] bf16 ----------
__global__ void prep_wres(const float* __restrict__ Wres, ushort16* __restrict__ Wres_b) {
  int idx = blockIdx.x * 256 + threadIdx.x;      // 12*64*3*1024 threads
  int n = idx & 1023;
  int d = (idx >> 10) % 3;
  int ck = idx / 3072;
  Wres_b[idx] = f2bf(Wres[((size_t)ck * 1024 + n) * 3 + d]);
}

// ---------- prep: x f32 -> xb bf16 (8 elems/thread) ----------
__global__ void xprep(const float* __restrict__ x, ushort16* __restrict__ xb) {
  int idx = blockIdx.x * 256 + threadIdx.x;      // 2,097,152 threads
  const float4* s = (const float4*)x + (size_t)idx * 2;
  float4 a = s[0], b = s[1];
  u32x4 o;
  o.x = pk2(a.x, a.y); o.y = pk2(a.z, a.w);
  o.z = pk2(b.x, b.y); o.w = pk2(b.z, b.w);
  ((u32x4*)xb)[idx] = o;
}

// ---------- MFMA GEMM: [16384 x 832] = xb @ Wall^T, fused y0/ybin epilogue ----------
// BM=128, BN=64 (= one group), BK=64; 4 waves 2x2; wave tile 64x32 (4x2 frags).
// LDS A[128][64] + B[64][64] bf16, XOR-swizzled (T2: byte ^= (row&7)<<4).
template<int XB>
__global__ __launch_bounds__(256) void gemm_mfma(
    const float* __restrict__ x, const ushort16* __restrict__ xb,
    const float* __restrict__ bfc, const float* __restrict__ bbin,
    const ushort16* __restrict__ Wall, ushort16* __restrict__ ybin,
    float* __restrict__ out) {
  __shared__ __align__(16) char smem[24576];     // A: 16384 B, B: 8192 B
  const int t = threadIdx.x;
  const int lane = t & 63, wid = t >> 6;
  const int wm = wid & 1, wn = wid >> 1;

  // XCD-bijective swizzle: 1664 = 8 * 208; n-fastest within chunk -> A-panel L2 reuse
  int orig = blockIdx.x;
  int bid = (orig & 7) * 208 + (orig >> 3);
  int nb = bid % 13, mb = bid / 13;
  const int b0 = mb * 128;

  f32x4 acc[4][2];
#pragma unroll
  for (int i = 0; i < 4; ++i)
#pragma unroll
    for (int j = 0; j < 2; ++j) acc[i][j] = (f32x4){0.f, 0.f, 0.f, 0.f};

  const int sxor = ((t >> 3) & 7) << 4;          // staging dest XOR (row&7 == (t>>3)&7)
  const int lr = lane & 15, lq = lane >> 4;
  const int fxor = (lr & 7) << 4;                // frag read XOR (row&7 == lr&7 for all frags)

  for (int kc = 0; kc < 1024; kc += 64) {
    __syncthreads();                             // readers done with previous tile
    // ---- stage A: 1024 x 16B slots (4 per thread) ----
#pragma unroll
    for (int i = 0; i < 4; ++i) {
      int s = t + i * 256;
      int row = s >> 3, c8 = (s & 7) * 8;        // c8: col in bf16 elems
      int dst = row * 128 + ((c8 * 2) ^ sxor);
      if (XB) {
        u32x4 v = *(const u32x4*)(xb + (size_t)(b0 + row) * 1024 + kc + c8);
        *(u32x4*)(smem + dst) = v;
      } else {
        const float4* src = (const float4*)(x + (size_t)(b0 + row) * 1024 + kc + c8);
        float4 v0 = src[0], v1 = src[1];
        u32x4 pv;
        pv.x = pk2(v0.x, v0.y); pv.y = pk2(v0.z, v0.w);
        pv.z = pk2(v1.x, v1.y); pv.w = pk2(v1.z, v1.w);
        *(u32x4*)(smem + dst) = pv;
      }
    }
    // ---- stage B: 512 x 16B slots (2 per thread) ----
#pragma unroll
    for (int i = 0; i < 2; ++i) {
      int s = t + i * 256;
      int row = s >> 3, c8 = (s & 7) * 8;
      int dst = 16384 + row * 128 + ((c8 * 2) ^ sxor);
      u32x4 v = *(const u32x4*)(Wall + (size_t)(nb * 64 + row) * 1024 + kc + c8);
      *(u32x4*)(smem + dst) = v;
    }
    __syncthreads();
    // ---- compute: 2 k-steps of 32 ----
#pragma unroll
    for (int kk = 0; kk < 2; ++kk) {
      int cbx = (kk * 64 + lq * 16) ^ fxor;
      bf16x8 af[4], bfr[2];
#pragma unroll
      for (int i = 0; i < 4; ++i) {
        int row = wm * 64 + i * 16 + lr;
        af[i] = *(const bf16x8*)(smem + row * 128 + cbx);
      }
#pragma unroll
      for (int j = 0; j < 2; ++j) {
        int row = wn * 32 + j * 16 + lr;
        bfr[j] = *(const bf16x8*)(smem + 16384 + row * 128 + cbx);
      }
#pragma unroll
      for (int i = 0; i < 4; ++i)
#pragma unroll
        for (int j = 0; j < 2; ++j)
          acc[i][j] = __builtin_amdgcn_mfma_f32_16x16x32_bf16(af[i], bfr[j], acc[i][j], 0, 0, 0);
    }
  }

  // ---- epilogue: C/D layout col=lane&15, row=(lane>>4)*4+r ----
#pragma unroll
  for (int i = 0; i < 4; ++i)
#pragma unroll
    for (int j = 0; j < 2; ++j)
#pragma unroll
      for (int r = 0; r < 4; ++r) {
        int gm = b0 + wm * 64 + i * 16 + lq * 4 + r;
        int col = wn * 32 + j * 16 + lr;
        float val = acc[i][j][r];
        if (nb == 0) {
          if (col < 12) out[(size_t)gm * 12 + col] = val + bfc[col];
        } else {
          int c = nb - 1;
          ybin[((size_t)gm * 12 + c) * 64 + col] = f2bf(val + bbin[c * 64 + col]);
        }
      }
}

// ---------- argmax (+f64 rescue) + selected residual + y1 ----------
__global__ __launch_bounds__(256) void select_kernel(
    const float* __restrict__ x, const float* __restrict__ Wbin,
    const float* __restrict__ bbin, const float* __restrict__ bres,
    const float* __restrict__ centers, const ushort16* __restrict__ Wres_b,
    const ushort16* __restrict__ ybin, float* __restrict__ out) {
  const int lane = threadIdx.x & 63;
  const int w = threadIdx.x >> 6;
  const int p = blockIdx.x * 4 + w;      // pair id < B*C
  const int b = p / 12, c = p % 12;

  float xv[16];
#pragma unroll
  for (int j = 0; j < 16; ++j) xv[j] = x[(size_t)b * 1024 + lane + 64 * j];

  float v = bf2f(ybin[(size_t)p * 64 + lane]);
  // wave-wide top-2 butterfly; ties -> smaller k (first-max)
  float m1 = v, m2 = -3.4e38f;
  int k1 = lane;
  for (int off = 32; off; off >>= 1) {
    float om1 = __shfl_xor(m1, off);
    int   ok1 = __shfl_xor(k1, off);
    float om2 = __shfl_xor(m2, off);
    bool take = (om1 > m1) || (om1 == m1 && ok1 < k1);
    float lose = take ? m1 : om1;
    m2 = fmaxf(fmaxf(m2, om2), lose);
    if (take) { m1 = om1; k1 = ok1; }
  }
  int ind = k1;
  if (m1 - m2 <= MARGIN) {
    unsigned long long mask = __ballot(v >= m1 - MARGIN);
    double best = -1.0e300;
    int bk = 0;
    while (mask) {
      int k = __ffsll(mask) - 1;
      mask &= (mask - 1);
      const float* wrow = Wbin + ((size_t)c * 64 + k) * 1024;
      double s = 0.0;
#pragma unroll
      for (int j = 0; j < 16; ++j)
        s += (double)xv[j] * (double)wrow[lane + 64 * j];
      for (int off = 32; off; off >>= 1) s += __shfl_xor(s, off);
      s += (double)bbin[c * 64 + k];
      if (s > best) { best = s; bk = k; }
    }
    ind = bk;
  }
  const ushort16* wr = Wres_b + ((size_t)(c * 64 + ind) * 3) * 1024;
  float a0 = 0.f, a1 = 0.f, a2 = 0.f;
#pragma unroll
  for (int j = 0; j < 16; ++j) {
    float xf = xv[j];
    int o = lane + 64 * j;
    a0 = fmaf(xf, bf2f(wr[o]),        a0);
    a1 = fmaf(xf, bf2f(wr[1024 + o]), a1);
    a2 = fmaf(xf, bf2f(wr[2048 + o]), a2);
  }
  for (int off = 32; off; off >>= 1) {
    a0 += __shfl_xor(a0, off);
    a1 += __shfl_xor(a1, off);
    a2 += __shfl_xor(a2, off);
  }
  if (lane == 0) {
    size_t base = (size_t)B_SZ * 12 + (size_t)b * 36;   // y1 region, [B][D][C]
    int ck = c * 64 + ind;
    out[base + 0 * 12 + c] = centers[ind * 3 + 0] + bres[ck * 3 + 0] + a0;
    out[base + 1 * 12 + c] = centers[ind * 3 + 1] + bres[ck * 3 + 1] + a1;
    out[base + 2 * 12 + c] = centers[ind * 3 + 2] + bres[ck * 3 + 2] + a2;
  }
}

extern "C" void kernel_launch(void* const* d_in, const int* in_sizes, int n_in,
                              void* d_out, int out_size, void* d_ws, size_t ws_size,
                              hipStream_t stream) {
  const float* x       = (const float*)d_in[0];
  const float* Wfc     = (const float*)d_in[1];
  const float* bfc     = (const float*)d_in[2];
  const float* Wbin    = (const float*)d_in[3];
  const float* bbin    = (const float*)d_in[4];
  const float* Wres    = (const float*)d_in[5];
  const float* bres    = (const float*)d_in[6];
  const float* centers = (const float*)d_in[7];
  float* out = (float*)d_out;

  char* ws = (char*)d_ws;
  ushort16* Wall   = (ushort16*)ws;                       // 1,703,936 B
  ushort16* Wres_b = (ushort16*)(ws + 1703936);           // 4,718,592 B
  ushort16* ybin   = (ushort16*)(ws + 6422528);           // 25,165,824 B
  ushort16* xb     = (ushort16*)(ws + 31588352);          // 33,554,432 B (optional)
  const bool use_xb = ws_size >= 65142784ull;

  prep_wall<<<3328, 256, 0, stream>>>(Wfc, Wbin, Wall);
  prep_wres<<<9216, 256, 0, stream>>>(Wres, Wres_b);
  if (use_xb) {
    xprep<<<8192, 256, 0, stream>>>(x, xb);
    gemm_mfma<1><<<1664, 256, 0, stream>>>(x, xb, bfc, bbin, Wall, ybin, out);
  } else {
    gemm_mfma<0><<<1664, 256, 0, stream>>>(x, xb, bfc, bbin, Wall, ybin, out);
  }
  select_kernel<<<49152, 256, 0, stream>>>(x, Wbin, bbin, bres, centers, Wres_b, ybin, out);
}

// Round 3
// 203.260 us; speedup vs baseline: 4.7816x; 1.2426x over previous
//
#include <hip/hip_runtime.h>

typedef unsigned int uint32;
typedef unsigned short ushort16;
typedef __attribute__((ext_vector_type(8))) short bf16x8;
typedef __attribute__((ext_vector_type(4))) float f32x4;
typedef __attribute__((ext_vector_type(4))) uint32 u32x4;

#define B_SZ 16384
#define MARGIN 0.04f

// ---------- bf16 helpers (manual RNE) ----------
__device__ __forceinline__ ushort16 f2bf(float f) {
  uint32 u = __float_as_uint(f);
  u += 0x7fffu + ((u >> 16) & 1u);
  return (ushort16)(u >> 16);
}
__device__ __forceinline__ float bf2f(ushort16 h) { return __uint_as_float(((uint32)h) << 16); }
__device__ __forceinline__ float bflo(uint32 u) { return __uint_as_float(u << 16); }
__device__ __forceinline__ float bfhi(uint32 u) { return __uint_as_float(u & 0xffff0000u); }
__device__ __forceinline__ uint32 pk2(float lo, float hi) {
  return ((uint32)f2bf(hi) << 16) | (uint32)f2bf(lo);
}

// ---------- prep: Wall = [Wfc^T (12) | 52 zeros | Wbin (768)] as bf16 ----------
__global__ void prep_wall(const float* __restrict__ Wfc, const float* __restrict__ Wbin,
                          ushort16* __restrict__ Wall) {
  int idx = blockIdx.x * 256 + threadIdx.x;      // 832*1024 threads
  int j = idx >> 10, n = idx & 1023;
  float v = 0.f;
  if (j < 12) v = Wfc[n * 12 + j];
  else if (j >= 64) v = Wbin[(size_t)(j - 64) * 1024 + n];
  Wall[idx] = f2bf(v);
}

// ---------- prep: Wres[c,k,n,d] -> Wres_b[c][k][d][n] bf16 ----------
__global__ void prep_wres(const float* __restrict__ Wres, ushort16* __restrict__ Wres_b) {
  int idx = blockIdx.x * 256 + threadIdx.x;      // 12*64*3*1024 threads
  int n = idx & 1023;
  int d = (idx >> 10) % 3;
  int ck = idx / 3072;
  Wres_b[idx] = f2bf(Wres[((size_t)ck * 1024 + n) * 3 + d]);
}

// ---------- prep: x f32 -> xb bf16 (8 elems/thread) ----------
__global__ void xprep(const float* __restrict__ x, ushort16* __restrict__ xb) {
  int idx = blockIdx.x * 256 + threadIdx.x;      // 2,097,152 threads
  const float4* s = (const float4*)x + (size_t)idx * 2;
  float4 a = s[0], b = s[1];
  u32x4 o;
  o.x = pk2(a.x, a.y); o.y = pk2(a.z, a.w);
  o.z = pk2(b.x, b.y); o.w = pk2(b.z, b.w);
  ((u32x4*)xb)[idx] = o;
}

// ---------- MFMA GEMM: [16384 x 832] = xb @ Wall^T, fused y0/ybin epilogue ----------
// BM=128, BN=64 (= one group), BK=64; 4 waves 2x2; wave tile 64x32 (4x2 frags).
// LDS layout: content[row][slot] = src[row][slot ^ (row&7)] (16B slots, T2 swizzle).
// XB=1: global_load_lds w/ pre-swizzled SOURCE slot (involution), linear LDS dest.
template<int XB>
__global__ __launch_bounds__(256) void gemm_mfma(
    const float* __restrict__ x, const ushort16* __restrict__ xb,
    const float* __restrict__ bfc, const float* __restrict__ bbin,
    const ushort16* __restrict__ Wall, ushort16* __restrict__ ybin,
    float* __restrict__ out) {
  __shared__ __align__(16) char smem[24576];     // A: 16384 B, B: 8192 B
  const int t = threadIdx.x;
  const int lane = t & 63, wid = t >> 6;
  const int wm = wid & 1, wn = wid >> 1;

  // XCD-bijective swizzle: 1664 = 8 * 208; n-fastest within chunk -> A-panel L2 reuse
  int orig = blockIdx.x;
  int bid = (orig & 7) * 208 + (orig >> 3);
  int nb = bid % 13, mb = bid / 13;
  const int b0 = mb * 128;

  f32x4 acc[4][2];
#pragma unroll
  for (int i = 0; i < 4; ++i)
#pragma unroll
    for (int j = 0; j < 2; ++j) acc[i][j] = (f32x4){0.f, 0.f, 0.f, 0.f};

  const int lr = lane & 15, lq = lane >> 4;
  const int fxor = (lr & 7) << 4;                // frag read XOR (row&7 == lr&7 for all frags)
  const int gs = (lane & 7) ^ (lane >> 3);       // pre-swizzled source slot for gload_lds
  const int grw = lane >> 3;                     // row-within-chunk

  for (int kc = 0; kc < 1024; kc += 64) {
    __syncthreads();                             // readers done with previous tile
    if (XB) {
      // ---- stage A: 16 chunks x 1024 B via global_load_lds ----
#pragma unroll
      for (int i = 0; i < 4; ++i) {
        int chunk = i * 4 + wid;
        int row = chunk * 8 + grw;
        const ushort16* src = xb + (size_t)(b0 + row) * 1024 + kc + gs * 8;
        __builtin_amdgcn_global_load_lds(
            (const __attribute__((address_space(1))) uint32*)src,
            (__attribute__((address_space(3))) uint32*)(smem + chunk * 1024), 16, 0, 0);
      }
      // ---- stage B: 8 chunks ----
#pragma unroll
      for (int i = 0; i < 2; ++i) {
        int chunk = i * 4 + wid;
        int row = chunk * 8 + grw;
        const ushort16* src = Wall + (size_t)(nb * 64 + row) * 1024 + kc + gs * 8;
        __builtin_amdgcn_global_load_lds(
            (const __attribute__((address_space(1))) uint32*)src,
            (__attribute__((address_space(3))) uint32*)(smem + 16384 + chunk * 1024), 16, 0, 0);
      }
    } else {
      const int sxor = ((t >> 3) & 7) << 4;
#pragma unroll
      for (int i = 0; i < 4; ++i) {
        int s = t + i * 256;
        int row = s >> 3, c8 = (s & 7) * 8;
        int dst = row * 128 + ((c8 * 2) ^ sxor);
        const float4* src = (const float4*)(x + (size_t)(b0 + row) * 1024 + kc + c8);
        float4 v0 = src[0], v1 = src[1];
        u32x4 pv;
        pv.x = pk2(v0.x, v0.y); pv.y = pk2(v0.z, v0.w);
        pv.z = pk2(v1.x, v1.y); pv.w = pk2(v1.z, v1.w);
        *(u32x4*)(smem + dst) = pv;
      }
#pragma unroll
      for (int i = 0; i < 2; ++i) {
        int s = t + i * 256;
        int row = s >> 3, c8 = (s & 7) * 8;
        int dst = 16384 + row * 128 + ((c8 * 2) ^ sxor);
        u32x4 v = *(const u32x4*)(Wall + (size_t)(nb * 64 + row) * 1024 + kc + c8);
        *(u32x4*)(smem + dst) = v;
      }
    }
    __syncthreads();
    // ---- compute: 2 k-steps of 32 ----
#pragma unroll
    for (int kk = 0; kk < 2; ++kk) {
      int cbx = (kk * 64 + lq * 16) ^ fxor;
      bf16x8 af[4], bfr[2];
#pragma unroll
      for (int i = 0; i < 4; ++i) {
        int row = wm * 64 + i * 16 + lr;
        af[i] = *(const bf16x8*)(smem + row * 128 + cbx);
      }
#pragma unroll
      for (int j = 0; j < 2; ++j) {
        int row = wn * 32 + j * 16 + lr;
        bfr[j] = *(const bf16x8*)(smem + 16384 + row * 128 + cbx);
      }
#pragma unroll
      for (int i = 0; i < 4; ++i)
#pragma unroll
        for (int j = 0; j < 2; ++j)
          acc[i][j] = __builtin_amdgcn_mfma_f32_16x16x32_bf16(af[i], bfr[j], acc[i][j], 0, 0, 0);
    }
  }

  // ---- epilogue: C/D layout col=lane&15, row=(lane>>4)*4+r ----
#pragma unroll
  for (int i = 0; i < 4; ++i)
#pragma unroll
    for (int j = 0; j < 2; ++j)
#pragma unroll
      for (int r = 0; r < 4; ++r) {
        int gm = b0 + wm * 64 + i * 16 + lq * 4 + r;
        int col = wn * 32 + j * 16 + lr;
        float val = acc[i][j][r];
        if (nb == 0) {
          if (col < 12) out[(size_t)gm * 12 + col] = val + bfc[col];
        } else {
          int c = nb - 1;
          ybin[((size_t)gm * 12 + c) * 64 + col] = f2bf(val + bbin[c * 64 + col]);
        }
      }
}

// ---------- per-b block: argmax (+f64 rescue) + selected residual + y1 ----------
// One block = one b; wave w handles c = 3w..3w+2. Dot layout: n = lane*16 + j.
__global__ __launch_bounds__(256) void select2(
    const float* __restrict__ x, const float* __restrict__ Wbin,
    const float* __restrict__ bbin, const float* __restrict__ bres,
    const float* __restrict__ centers, const ushort16* __restrict__ Wres_b,
    const ushort16* __restrict__ ybin, float* __restrict__ out) {
  const int lane = threadIdx.x & 63;
  const int w = threadIdx.x >> 6;
  const int b = blockIdx.x;

  // x row: lane reads 16 contiguous floats (4 x float4); 4 waves share via L1
  float xv[16];
  {
    const float4* xr = (const float4*)(x + (size_t)b * 1024 + lane * 16);
#pragma unroll
    for (int q = 0; q < 4; ++q) {
      float4 v = xr[q];
      xv[4 * q + 0] = v.x; xv[4 * q + 1] = v.y; xv[4 * q + 2] = v.z; xv[4 * q + 3] = v.w;
    }
  }
  const size_t obase = (size_t)B_SZ * 12 + (size_t)b * 36;

#pragma unroll 1
  for (int cc = 0; cc < 3; ++cc) {
    const int c = w * 3 + cc;
    float v = bf2f(ybin[((size_t)b * 12 + c) * 64 + lane]);
    // wave-wide top-2 butterfly; ties -> smaller k (first-max)
    float m1 = v, m2 = -3.4e38f;
    int k1 = lane;
    for (int off = 32; off; off >>= 1) {
      float om1 = __shfl_xor(m1, off);
      int   ok1 = __shfl_xor(k1, off);
      float om2 = __shfl_xor(m2, off);
      bool take = (om1 > m1) || (om1 == m1 && ok1 < k1);
      float lose = take ? m1 : om1;
      m2 = fmaxf(fmaxf(m2, om2), lose);
      if (take) { m1 = om1; k1 = ok1; }
    }
    int ind = k1;
    if (m1 - m2 <= MARGIN) {
      // exact f64 rescue over candidate k's
      unsigned long long mask = __ballot(v >= m1 - MARGIN);
      double best = -1.0e300;
      int bk = 0;
      while (mask) {
        int k = __ffsll(mask) - 1;
        mask &= (mask - 1);
        const float4* wr4 = (const float4*)(Wbin + ((size_t)c * 64 + k) * 1024 + lane * 16);
        double s = 0.0;
#pragma unroll
        for (int q = 0; q < 4; ++q) {
          float4 wv = wr4[q];
          s += (double)xv[4 * q + 0] * (double)wv.x + (double)xv[4 * q + 1] * (double)wv.y +
               (double)xv[4 * q + 2] * (double)wv.z + (double)xv[4 * q + 3] * (double)wv.w;
        }
        for (int off = 32; off; off >>= 1) s += __shfl_xor(s, off);
        s += (double)bbin[c * 64 + k];
        if (s > best) { best = s; bk = k; }   // ascending k + strict > = first max
      }
      ind = bk;
    }
    // selected residual: dot over n = lane*16 + j, vectorized bf16x8 reads
    const ushort16* wr = Wres_b + ((size_t)(c * 64 + ind) * 3) * 1024;
    float a[3] = {0.f, 0.f, 0.f};
#pragma unroll
    for (int d = 0; d < 3; ++d) {
      const u32x4* p = (const u32x4*)(wr + d * 1024 + lane * 16);
      u32x4 w0 = p[0], w1 = p[1];
      uint32 uw[8] = {w0.x, w0.y, w0.z, w0.w, w1.x, w1.y, w1.z, w1.w};
#pragma unroll
      for (int q = 0; q < 8; ++q) {
        a[d] = fmaf(xv[2 * q],     bflo(uw[q]), a[d]);
        a[d] = fmaf(xv[2 * q + 1], bfhi(uw[q]), a[d]);
      }
    }
    for (int off = 32; off; off >>= 1) {
      a[0] += __shfl_xor(a[0], off);
      a[1] += __shfl_xor(a[1], off);
      a[2] += __shfl_xor(a[2], off);
    }
    if (lane == 0) {
      int ck = c * 64 + ind;
      out[obase + 0 * 12 + c] = centers[ind * 3 + 0] + bres[ck * 3 + 0] + a[0];
      out[obase + 1 * 12 + c] = centers[ind * 3 + 1] + bres[ck * 3 + 1] + a[1];
      out[obase + 2 * 12 + c] = centers[ind * 3 + 2] + bres[ck * 3 + 2] + a[2];
    }
  }
}

extern "C" void kernel_launch(void* const* d_in, const int* in_sizes, int n_in,
                              void* d_out, int out_size, void* d_ws, size_t ws_size,
                              hipStream_t stream) {
  const float* x       = (const float*)d_in[0];
  const float* Wfc     = (const float*)d_in[1];
  const float* bfc     = (const float*)d_in[2];
  const float* Wbin    = (const float*)d_in[3];
  const float* bbin    = (const float*)d_in[4];
  const float* Wres    = (const float*)d_in[5];
  const float* bres    = (const float*)d_in[6];
  const float* centers = (const float*)d_in[7];
  float* out = (float*)d_out;

  char* ws = (char*)d_ws;
  ushort16* Wall   = (ushort16*)ws;                       // 1,703,936 B
  ushort16* Wres_b = (ushort16*)(ws + 1703936);           // 4,718,592 B
  ushort16* ybin   = (ushort16*)(ws + 6422528);           // 25,165,824 B
  ushort16* xb     = (ushort16*)(ws + 31588352);          // 33,554,432 B (optional)
  const bool use_xb = ws_size >= 65142784ull;

  prep_wall<<<3328, 256, 0, stream>>>(Wfc, Wbin, Wall);
  prep_wres<<<9216, 256, 0, stream>>>(Wres, Wres_b);
  if (use_xb) {
    xprep<<<8192, 256, 0, stream>>>(x, xb);
    gemm_mfma<1><<<1664, 256, 0, stream>>>(x, xb, bfc, bbin, Wall, ybin, out);
  } else {
    gemm_mfma<0><<<1664, 256, 0, stream>>>(x, xb, bfc, bbin, Wall, ybin, out);
  }
  select2<<<B_SZ, 256, 0, stream>>>(x, Wbin, bbin, bres, centers, Wres_b, ybin, out);
}